// Round 1
// baseline (1709.521 us; speedup 1.0000x reference)
//
#include <hip/hip_runtime.h>
#include <hip/hip_bf16.h>

// Problem constants
#define DIMD 512
#define KCODES 1024
#define NB 16
#define NT 4096
#define NROWS (NB*NT)            // 65536

// d_out float offsets (outputs concatenated flat, all read as f32)
#define O_QUANT 0
#define O_IDX   33554432
#define O_LOSS  33619968
#define O_PERP  33619969
#define O_NCB   33619970
#define O_NSIZE 34144258
#define O_NSUM  34145282

// ws float offsets
#define W_CSIZE 65536            // first 65536 floats-worth = int idx[65536]
#define W_CSUM  66560
#define W_NORM  590848
#define W_SCAL  591872           // [0]=n_total, [1]=loss_sum

// ---------------- K1: codebook row norms ----------------
__global__ void k_norms(const float* __restrict__ cb, float* __restrict__ norms) {
    int k = blockIdx.x;
    int lane = threadIdx.x;           // 64
    const float* row = cb + (size_t)k * DIMD;
    float4 a = make_float4(0.f, 0.f, 0.f, 0.f);
    for (int d = lane * 4; d < DIMD; d += 64 * 4) {
        float4 v = *(const float4*)(row + d);
        a.x += v.x * v.x; a.y += v.y * v.y; a.z += v.z * v.z; a.w += v.w * v.w;
    }
    float s = (a.x + a.y) + (a.z + a.w);
    for (int m = 32; m; m >>= 1) s += __shfl_xor(s, m);
    if (lane == 0) norms[k] = s;
}

// ---------------- K2: distances + argmin + scatter ----------------
// Block: 64 rows (one b, 64 consecutive t), 512 threads = 16(ty) x 32(tx).
// Thread tile: 4 rows (ty+16i) x 2 codes (tx+32j). X-tile fully in LDS.
__launch_bounds__(512, 1)
__global__ void k_argmin(const float* __restrict__ x,
                         const float* __restrict__ cb,
                         const float* __restrict__ norms,
                         int*   __restrict__ idx_ws,
                         float* __restrict__ out_idx,
                         float* __restrict__ csize,
                         float* __restrict__ csum) {
    __shared__ float x_lds[64][516];       // +4 pad: rows land on different banks
    __shared__ float e_lds[2][64][36];     // 64 codes x 32 d, +4 pad, double-buffered
    __shared__ int   code_sh[64];

    const int tid = threadIdx.x;
    const int blk = blockIdx.x;
    const int n0 = blk * 64;
    const int b  = n0 >> 12;
    const int t0 = n0 & 4095;
    const float* xb = x + (size_t)b * DIMD * NT + t0;

    // ---- load X tile (coalesced over t, transposed into LDS) ----
    {
        const int t = tid & 63, dg = tid >> 6;    // dg: 0..7
        for (int k2 = 0; k2 < 64; ++k2) {
            int d = dg * 64 + k2;
            x_lds[t][d] = xb[(size_t)d * NT + t];
        }
    }

    const int ty = tid >> 5;          // 0..15
    const int tx = tid & 31;          // 0..31
    const int c_local = tid >> 3;     // 0..63 (staging)
    const int dsub    = (tid & 7) << 2;

    float bestv[4];
    int   bestc[4];
#pragma unroll
    for (int i = 0; i < 4; ++i) { bestv[i] = 3.0e38f; bestc[i] = 0; }

    // prologue: stage 0 into buf0, prefetch stage 1
    float4 reg = *(const float4*)(cb + (size_t)c_local * DIMD + dsub);
    __syncthreads();                                  // x_lds complete
    *(float4*)&e_lds[0][c_local][dsub] = reg;
    reg = *(const float4*)(cb + (size_t)c_local * DIMD + 32 + dsub);
    __syncthreads();                                  // buf0 visible

    float4 acc[4][2];
    for (int s = 0; s < 256; ++s) {                   // s = ct*16 + dt
        const int ct = s >> 4, dt = s & 15;
        if (s + 1 < 256)
            *(float4*)&e_lds[(s + 1) & 1][c_local][dsub] = reg;
        if (s + 2 < 256) {
            const int s2 = s + 2;
            reg = *(const float4*)(cb + (size_t)(((s2 >> 4) * 64) + c_local) * DIMD
                                      + ((s2 & 15) * 32) + dsub);
        }
        if (dt == 0) {
#pragma unroll
            for (int i = 0; i < 4; ++i)
#pragma unroll
                for (int j = 0; j < 2; ++j) acc[i][j] = make_float4(0.f, 0.f, 0.f, 0.f);
        }
        const int buf = s & 1;
        const int dbase = dt * 32;
#pragma unroll
        for (int d4 = 0; d4 < 8; ++d4) {
            const int d = dbase + d4 * 4;
            float4 xv[4], ev[2];
#pragma unroll
            for (int i = 0; i < 4; ++i) xv[i] = *(const float4*)&x_lds[ty + 16 * i][d];
#pragma unroll
            for (int j = 0; j < 2; ++j) ev[j] = *(const float4*)&e_lds[buf][tx + 32 * j][d4 * 4];
#pragma unroll
            for (int i = 0; i < 4; ++i)
#pragma unroll
                for (int j = 0; j < 2; ++j) {
                    acc[i][j].x += xv[i].x * ev[j].x;
                    acc[i][j].y += xv[i].y * ev[j].y;
                    acc[i][j].z += xv[i].z * ev[j].z;
                    acc[i][j].w += xv[i].w * ev[j].w;
                }
        }
        if (dt == 15) {
            const float n0v = norms[ct * 64 + tx];
            const float n1v = norms[ct * 64 + tx + 32];
            const int c0 = ct * 64 + tx;
            const int c1 = c0 + 32;
#pragma unroll
            for (int i = 0; i < 4; ++i) {
                float d0 = (acc[i][0].x + acc[i][0].y) + (acc[i][0].z + acc[i][0].w);
                float d1 = (acc[i][1].x + acc[i][1].y) + (acc[i][1].z + acc[i][1].w);
                float s0 = n0v - 2.0f * d0;
                float s1 = n1v - 2.0f * d1;
                if (s0 < bestv[i]) { bestv[i] = s0; bestc[i] = c0; }  // ascending code order:
                if (s1 < bestv[i]) { bestv[i] = s1; bestc[i] = c1; }  // strict < keeps lowest idx
            }
        }
        __syncthreads();
    }

    // ---- argmin reduce across the 32 tx lanes (prefer lower code on tie) ----
#pragma unroll
    for (int i = 0; i < 4; ++i) {
        float v = bestv[i]; int c = bestc[i];
#pragma unroll
        for (int m = 16; m; m >>= 1) {
            float ov = __shfl_xor(v, m);
            int   oc = __shfl_xor(c, m);
            if (ov < v || (ov == v && oc < c)) { v = ov; c = oc; }
        }
        if (tx == 0) code_sh[ty + 16 * i] = c;
    }
    __syncthreads();

    if (tid < 64) {
        const int c = code_sh[tid];
        idx_ws[n0 + tid] = c;
        out_idx[n0 + tid] = (float)c;
        atomicAdd(&csize[c], 1.0f);
    }
    // scatter cluster_sum from the LDS-resident X tile
    const int w = tid >> 6, lane = tid & 63;
    for (int rr = 0; rr < 8; ++rr) {
        const int r = w * 8 + rr;
        const int c = code_sh[r];
        float* dst = csum + (size_t)c * DIMD;
#pragma unroll
        for (int q = 0; q < 8; ++q) {
            const int d = lane + q * 64;
            atomicAdd(dst + d, x_lds[r][d]);
        }
    }
}

// ---------------- K4a: new_ema_size, n, perplexity ----------------
__global__ void k_ema_size(const float* __restrict__ csize,
                           const float* __restrict__ ema_size,
                           float* __restrict__ out, float* __restrict__ scal) {
    __shared__ float red[1024];
    const int k = threadIdx.x;
    const float cs = csize[k];
    const float ns = ema_size[k] * 0.99f + 0.01f * cs;
    out[O_NSIZE + k] = ns;
    red[k] = ns;
    __syncthreads();
    for (int s = 512; s > 0; s >>= 1) {
        if (k < s) red[k] += red[k + s];
        __syncthreads();
    }
    if (k == 0) scal[0] = red[0];
    __syncthreads();
    const float p = cs * (1.0f / 65536.0f);   // sum(cluster_size)==65536 exactly
    red[k] = -p * logf(p + 1e-10f);
    __syncthreads();
    for (int s = 512; s > 0; s >>= 1) {
        if (k < s) red[k] += red[k + s];
        __syncthreads();
    }
    if (k == 0) out[O_PERP] = expf(red[0]);
}

// ---------------- K4b: new_ema_sum + new_codebook ----------------
__global__ void k_codebook(const float* __restrict__ csum,
                           const float* __restrict__ ema_sum,
                           const float* __restrict__ scal,
                           float* __restrict__ out) {
    const int gid = blockIdx.x * 256 + threadIdx.x;   // < 524288
    const int k = gid >> 9;
    const float n = scal[0];
    const float ns = out[O_NSIZE + k];
    const float smoothed = (ns + 1e-5f) / (n + KCODES * 1e-5f) * n;
    const float nes = ema_sum[gid] * 0.99f + 0.01f * csum[gid];
    out[O_NSUM + gid] = nes;
    out[O_NCB + gid]  = nes / smoothed;
}

// ---------------- K5: quantized + commitment loss ----------------
__launch_bounds__(256, 4)
__global__ void k_quant(const float* __restrict__ x,
                        const int* __restrict__ idx_ws,
                        const float* __restrict__ ncb,   // d_out + O_NCB (scalar reads only)
                        float* __restrict__ out_q,
                        float* __restrict__ loss_sum) {
    __shared__ float q_lds[64][65];
    __shared__ int   codes[64];
    __shared__ float wred[4];
    const int tid = threadIdx.x;
    const int n0 = blockIdx.x * 64;
    const int b = n0 >> 12, t0 = n0 & 4095;
    if (tid < 64) codes[tid] = idx_ws[n0 + tid];
    __syncthreads();
    const float* xb = x + (size_t)b * DIMD * NT + t0;
    float* qb = out_q + (size_t)b * DIMD * NT + t0;
    const int w = tid >> 6, lane = tid & 63;
    const int t = tid & 63, dg = tid >> 6;
    float lsum = 0.f;
    for (int dc = 0; dc < 8; ++dc) {
        for (int rr = 0; rr < 16; ++rr) {          // wave w stages 16 codebook rows
            const int r = w * 16 + rr;
            q_lds[r][lane] = ncb[(size_t)codes[r] * DIMD + dc * 64 + lane];
        }
        __syncthreads();
        for (int m = 0; m < 16; ++m) {
            const int dl = dg * 16 + m;
            const int d = dc * 64 + dl;
            const float xv = xb[(size_t)d * NT + t];
            const float qv = q_lds[t][dl];
            qb[(size_t)d * NT + t] = qv;
            const float df = xv - qv;
            lsum += df * df;
        }
        __syncthreads();
    }
    for (int m = 32; m; m >>= 1) lsum += __shfl_xor(lsum, m);
    if (lane == 0) wred[w] = lsum;
    __syncthreads();
    if (tid == 0) atomicAdd(loss_sum, (wred[0] + wred[1]) + (wred[2] + wred[3]));
}

// ---------------- K6: finalize loss ----------------
__global__ void k_final(const float* __restrict__ scal, float* __restrict__ out) {
    out[O_LOSS] = scal[1] * (1.0f / 33554432.0f);
}

extern "C" void kernel_launch(void* const* d_in, const int* in_sizes, int n_in,
                              void* d_out, int out_size, void* d_ws, size_t ws_size,
                              hipStream_t stream) {
    const float* x        = (const float*)d_in[0];
    const float* cbw      = (const float*)d_in[1];
    const float* ema_size = (const float*)d_in[2];
    const float* ema_sum  = (const float*)d_in[3];
    float* out = (float*)d_out;
    float* wsf = (float*)d_ws;
    int*   widx = (int*)d_ws;
    float* csize = wsf + W_CSIZE;
    float* csum  = wsf + W_CSUM;
    float* norms = wsf + W_NORM;
    float* scal  = wsf + W_SCAL;

    // zero accumulators (csize + csum + norms + scalars)
    hipMemsetAsync(csize, 0, (size_t)(W_SCAL + 8 - W_CSIZE) * sizeof(float), stream);

    k_norms  <<<KCODES, 64, 0, stream>>>(cbw, norms);
    k_argmin <<<NROWS / 64, 512, 0, stream>>>(x, cbw, norms, widx, out + O_IDX, csize, csum);
    k_ema_size<<<1, 1024, 0, stream>>>(csize, ema_size, out, scal);
    k_codebook<<<(KCODES * DIMD) / 256, 256, 0, stream>>>(csum, ema_sum, scal, out);
    k_quant  <<<NROWS / 64, 256, 0, stream>>>(x, widx, out + O_NCB, out, scal + 1);
    k_final  <<<1, 1, 0, stream>>>(scal, out);
}

// Round 4
// 757.368 us; speedup vs baseline: 2.2572x; 2.2572x over previous
//
#include <hip/hip_runtime.h>
#include <hip/hip_bf16.h>

// Problem constants
#define DIMD 512
#define KCODES 1024
#define NB 16
#define NT 4096
#define NROWS (NB*NT)            // 65536

// d_out float offsets (outputs concatenated flat, all read as f32)
#define O_QUANT 0
#define O_IDX   33554432
#define O_LOSS  33619968
#define O_PERP  33619969
#define O_NCB   33619970
#define O_NSIZE 34144258
#define O_NSUM  34145282

// ws float offsets
#define W_CSIZE 65536            // first 65536 floats-worth = int idx[65536]
#define W_CSUM  66560
#define W_NORM  590848
#define W_SCAL  591872           // [0]=n_total, [1]=loss_sum
#define W_FLAGCNT 591880         // int
#define W_FLAGS   591881         // int[65536]
#define W_BPH  657424            // ushort[524288] = 1 MB (16B aligned)
// Bpl = Bph + 524288 ushorts

#define EPS_FLAG 1.5e-3f

typedef __attribute__((ext_vector_type(8))) short bf16x8;
typedef __attribute__((ext_vector_type(4))) float f32x4;

static __device__ __forceinline__ ushort f2bf(float f) {
    unsigned u = __float_as_uint(f);
    unsigned r = (u + 0x7fffu + ((u >> 16) & 1u)) >> 16;
    return (ushort)r;
}
static __device__ __forceinline__ float bf2f(ushort h) {
    return __uint_as_float(((unsigned)h) << 16);
}

// ---------------- K0: pack codebook into MFMA-fragment order, bf16 hi/lo ----------------
// Bp[ns(64)][kc(16)][lane(64)][j(8)]: lane l <-> code ns*16+(l&15), k = kc*32+(l>>4)*8+j
__global__ void k_pack(const float* __restrict__ cb,
                       ushort* __restrict__ Bph, ushort* __restrict__ Bpl) {
    const int blk = blockIdx.x;        // 1024 = ns(64) * kc(16)
    const int ns = blk >> 4, kc = blk & 15;
    const int lane = threadIdx.x;      // 64
    const int c = ns * 16 + (lane & 15);
    const int kbase = kc * 32 + ((lane >> 4) << 3);
    const size_t off = (((size_t)ns * 16 + kc) * 64 + lane) * 8;
#pragma unroll
    for (int j = 0; j < 8; ++j) {
        const float v = cb[(size_t)c * DIMD + kbase + j];
        const ushort h = f2bf(v);
        Bph[off + j] = h;
        Bpl[off + j] = f2bf(v - bf2f(h));
    }
}

// ---------------- K1: codebook row norms ----------------
__global__ void k_norms(const float* __restrict__ cb, float* __restrict__ norms) {
    int k = blockIdx.x;
    int lane = threadIdx.x;           // 64
    const float* row = cb + (size_t)k * DIMD;
    float4 a = make_float4(0.f, 0.f, 0.f, 0.f);
    for (int d = lane * 4; d < DIMD; d += 64 * 4) {
        float4 v = *(const float4*)(row + d);
        a.x += v.x * v.x; a.y += v.y * v.y; a.z += v.z * v.z; a.w += v.w * v.w;
    }
    float s = (a.x + a.y) + (a.z + a.w);
    for (int m = 32; m; m >>= 1) s += __shfl_xor(s, m);
    if (lane == 0) norms[k] = s;
}

// ---------------- K2: MFMA distances + argmin(top2) + scatter ----------------
// Block: 64 rows, 512 threads = 8 waves. Wave wn handles codes wn*128..+128
// (8 subtiles of 16) x all 64 rows (4 subtiles of 16). 3-split bf16 MFMA.
__launch_bounds__(512, 2)
__global__ void k_gemm_argmin(const float* __restrict__ x,
                              const ushort* __restrict__ Bph,
                              const ushort* __restrict__ Bpl,
                              const float* __restrict__ norms,
                              int*   __restrict__ idx_ws,
                              float* __restrict__ out_idx,
                              float* __restrict__ csize,
                              float* __restrict__ csum,
                              int*   __restrict__ flag_cnt,
                              int*   __restrict__ flags) {
    // A fragment image: [split][sub(4 of 16 rows)][kc(16)][lane][j] bf16 = 128 KB
    __shared__ ushort A_sh[2][4][16][64][8];
    __shared__ float part_v1[8][64], part_v2[8][64];
    __shared__ int   part_c1[8][64];
    __shared__ int   code_sh[64];

    const int tid = threadIdx.x;
    const int n0 = blockIdx.x * 64;
    const int b = n0 >> 12, t0 = n0 & 4095;
    const float* xb = x + (size_t)b * DIMD * NT + t0;

    // ---- phase 1: transpose-split x slice into fragment layout ----
    {
        const int t = tid & 63, dg = tid >> 6;
        const int sub = t >> 4, m = t & 15;
        for (int i = 0; i < 64; ++i) {
            const int d = dg * 64 + i;
            const float v = xb[(size_t)d * NT + t];
            const ushort h = f2bf(v);
            const ushort l = f2bf(v - bf2f(h));
            const int kc = d >> 5, ko = d & 31;
            const int ln = m + ((ko >> 3) << 4), j = ko & 7;
            A_sh[0][sub][kc][ln][j] = h;
            A_sh[1][sub][kc][ln][j] = l;
        }
    }
    __syncthreads();

    const int wn = tid >> 6;
    const int lane = tid & 63;

    f32x4 acc[4][8];
#pragma unroll
    for (int m = 0; m < 4; ++m)
#pragma unroll
        for (int s = 0; s < 8; ++s) acc[m][s] = (f32x4){0.f, 0.f, 0.f, 0.f};

    // ---- main loop: no barriers, MFMA-bound ----
    for (int kc = 0; kc < 16; ++kc) {
        bf16x8 ah[4], al[4];
#pragma unroll
        for (int m = 0; m < 4; ++m) {
            ah[m] = *(const bf16x8*)&A_sh[0][m][kc][lane][0];
            al[m] = *(const bf16x8*)&A_sh[1][m][kc][lane][0];
        }
#pragma unroll
        for (int s = 0; s < 8; ++s) {
            const int ns = wn * 8 + s;
            const size_t boff = (((size_t)ns * 16 + kc) * 64 + lane) * 8;
            const bf16x8 bh = *(const bf16x8*)(Bph + boff);
            const bf16x8 bl = *(const bf16x8*)(Bpl + boff);
#pragma unroll
            for (int m = 0; m < 4; ++m) {
                acc[m][s] = __builtin_amdgcn_mfma_f32_16x16x32_bf16(ah[m], bh, acc[m][s], 0, 0, 0);
                acc[m][s] = __builtin_amdgcn_mfma_f32_16x16x32_bf16(ah[m], bl, acc[m][s], 0, 0, 0);
                acc[m][s] = __builtin_amdgcn_mfma_f32_16x16x32_bf16(al[m], bh, acc[m][s], 0, 0, 0);
            }
        }
    }

    // ---- epilogue: per-lane top-2 over this wave's 128 codes ----
    const int col = lane & 15, kg = lane >> 4;
    float v1[16], v2[16]; int c1[16];
#pragma unroll
    for (int q = 0; q < 16; ++q) { v1[q] = 3e38f; v2[q] = 3e38f; c1[q] = 0; }
#pragma unroll
    for (int s = 0; s < 8; ++s) {
        const int cbase = wn * 128 + s * 16 + col;
        const float nrm = norms[cbase];
#pragma unroll
        for (int m = 0; m < 4; ++m)
#pragma unroll
            for (int r = 0; r < 4; ++r) {
                const float sc = fmaf(-2.0f, acc[m][s][r], nrm);
                const int q = m * 4 + r;
                if (sc < v1[q]) { v2[q] = v1[q]; v1[q] = sc; c1[q] = cbase; }
                else if (sc < v2[q]) v2[q] = sc;
            }
    }
    // merge across the 16 col-lanes (C/D layout: col = lane&15)
#pragma unroll
    for (int q = 0; q < 16; ++q) {
        float a1 = v1[q], a2 = v2[q]; int ac = c1[q];
#pragma unroll
        for (int msk = 1; msk <= 8; msk <<= 1) {
            const float b1 = __shfl_xor(a1, msk);
            const float b2 = __shfl_xor(a2, msk);
            const int   bc = __shfl_xor(ac, msk);
            const bool bwin = (b1 < a1) || (b1 == a1 && bc < ac);
            const float lose = bwin ? a1 : b1;
            a2 = fminf(fminf(a2, b2), lose);
            if (bwin) { a1 = b1; ac = bc; }
        }
        if (col == 0) {
            const int row = (q >> 2) * 16 + kg * 4 + (q & 3);   // m*16 + kg*4 + r
            part_v1[wn][row] = a1; part_v2[wn][row] = a2; part_c1[wn][row] = ac;
        }
    }
    __syncthreads();

    // ---- cross-wave merge, emit index, flag near-ties ----
    if (tid < 64) {
        float bv1 = 3e38f, bv2 = 3e38f; int bc = 0;
#pragma unroll
        for (int w = 0; w < 8; ++w) {
            const float q1 = part_v1[w][tid], q2 = part_v2[w][tid];
            const int qc = part_c1[w][tid];
            const bool win = (q1 < bv1) || (q1 == bv1 && qc < bc);
            const float lose = win ? bv1 : q1;
            bv2 = fminf(bv2, fminf(q2, lose));
            if (win) { bv1 = q1; bc = qc; }
        }
        code_sh[tid] = bc;
        const int n = n0 + tid;
        idx_ws[n] = bc;
        out_idx[n] = (float)bc;
        atomicAdd(&csize[bc], 1.0f);
        if (bv2 - bv1 < EPS_FLAG) {
            const int p = atomicAdd(flag_cnt, 1);
            flags[p] = n;
        }
    }
    __syncthreads();

    // ---- scatter cluster_sum (x reconstructed from hi+lo, err ~2^-18) ----
    const int w8 = tid >> 6, ln2 = tid & 63;
    for (int rr = 0; rr < 8; ++rr) {
        const int r = w8 * 8 + rr;
        const int c = code_sh[r];
        float* dst = csum + (size_t)c * DIMD;
        const int sub = r >> 4, m = r & 15;
#pragma unroll
        for (int qq = 0; qq < 8; ++qq) {
            const int d = ln2 + (qq << 6);
            const int kc = d >> 5, ko = d & 31;
            const int ln = m + ((ko >> 3) << 4), j = ko & 7;
            const float xv = bf2f(A_sh[0][sub][kc][ln][j]) + bf2f(A_sh[1][sub][kc][ln][j]);
            atomicAdd(dst + d, xv);
        }
    }
}

// ---------------- K3: exact fp32 recompute for near-tie rows ----------------
__global__ void k_refine(const float* __restrict__ x,
                         const float* __restrict__ cb,
                         const float* __restrict__ norms,
                         const int* __restrict__ flag_cnt,
                         const int* __restrict__ flags,
                         int*   __restrict__ idx_ws,
                         float* __restrict__ out_idx,
                         float* __restrict__ csize,
                         float* __restrict__ csum) {
    __shared__ float x_sh[512];
    __shared__ float rv[256];
    __shared__ int   rc[256];
    __shared__ int   cold_sh;
    const int tid = threadIdx.x;
    const int cnt = flag_cnt[0];
    for (int i = blockIdx.x; i < cnt; i += gridDim.x) {
        const int n = flags[i];
        const int b = n >> 12, t = n & 4095;
        for (int d = tid; d < 512; d += 256)
            x_sh[d] = x[(size_t)b * DIMD * NT + (size_t)d * NT + t];
        if (tid == 0) cold_sh = idx_ws[n];
        __syncthreads();
        float bv = 3e38f; int bc = 0;
        for (int c = tid; c < 1024; c += 256) {
            const float* e = cb + (size_t)c * DIMD;
            float4 a = make_float4(0.f, 0.f, 0.f, 0.f);
            for (int d = 0; d < 512; d += 4) {
                a.x += x_sh[d + 0] * e[d + 0]; a.y += x_sh[d + 1] * e[d + 1];
                a.z += x_sh[d + 2] * e[d + 2]; a.w += x_sh[d + 3] * e[d + 3];
            }
            const float sc = norms[c] - 2.0f * ((a.x + a.y) + (a.z + a.w));
            if (sc < bv) { bv = sc; bc = c; }   // c ascending per thread: strict <
        }
        rv[tid] = bv; rc[tid] = bc;
        __syncthreads();
        for (int s2 = 128; s2 > 0; s2 >>= 1) {
            if (tid < s2) {
                const float ov = rv[tid + s2]; const int oc = rc[tid + s2];
                if (ov < rv[tid] || (ov == rv[tid] && oc < rc[tid])) { rv[tid] = ov; rc[tid] = oc; }
            }
            __syncthreads();
        }
        const int cnew = rc[0];
        const int cold = cold_sh;
        if (cnew != cold) {
            if (tid == 0) {
                idx_ws[n] = cnew;
                out_idx[n] = (float)cnew;
                atomicAdd(&csize[cold], -1.0f);
                atomicAdd(&csize[cnew], 1.0f);
            }
            for (int d = tid; d < 512; d += 256) {
                atomicAdd(&csum[(size_t)cold * DIMD + d], -x_sh[d]);
                atomicAdd(&csum[(size_t)cnew * DIMD + d],  x_sh[d]);
            }
        }
        __syncthreads();
    }
}

// ---------------- K4a: new_ema_size, n, perplexity ----------------
__global__ void k_ema_size(const float* __restrict__ csize,
                           const float* __restrict__ ema_size,
                           float* __restrict__ out, float* __restrict__ scal) {
    __shared__ float red[1024];
    const int k = threadIdx.x;
    const float cs = csize[k];
    const float ns = ema_size[k] * 0.99f + 0.01f * cs;
    out[O_NSIZE + k] = ns;
    red[k] = ns;
    __syncthreads();
    for (int s = 512; s > 0; s >>= 1) {
        if (k < s) red[k] += red[k + s];
        __syncthreads();
    }
    if (k == 0) scal[0] = red[0];
    __syncthreads();
    const float p = cs * (1.0f / 65536.0f);
    red[k] = -p * logf(p + 1e-10f);
    __syncthreads();
    for (int s = 512; s > 0; s >>= 1) {
        if (k < s) red[k] += red[k + s];
        __syncthreads();
    }
    if (k == 0) out[O_PERP] = expf(red[0]);
}

// ---------------- K4b: new_ema_sum + new_codebook ----------------
__global__ void k_codebook(const float* __restrict__ csum,
                           const float* __restrict__ ema_sum,
                           const float* __restrict__ scal,
                           float* __restrict__ out) {
    const int gid = blockIdx.x * 256 + threadIdx.x;   // < 524288
    const int k = gid >> 9;
    const float n = scal[0];
    const float ns = out[O_NSIZE + k];
    const float smoothed = (ns + 1e-5f) / (n + KCODES * 1e-5f) * n;
    const float nes = ema_sum[gid] * 0.99f + 0.01f * csum[gid];
    out[O_NSUM + gid] = nes;
    out[O_NCB + gid]  = nes / smoothed;
}

// ---------------- K5: quantized + commitment loss ----------------
__launch_bounds__(256, 4)
__global__ void k_quant(const float* __restrict__ x,
                        const int* __restrict__ idx_ws,
                        const float* __restrict__ ncb,
                        float* __restrict__ out_q,
                        float* __restrict__ loss_sum) {
    __shared__ float q_lds[64][65];
    __shared__ int   codes[64];
    __shared__ float wred[4];
    const int tid = threadIdx.x;
    const int n0 = blockIdx.x * 64;
    const int b = n0 >> 12, t0 = n0 & 4095;
    if (tid < 64) codes[tid] = idx_ws[n0 + tid];
    __syncthreads();
    const float* xb = x + (size_t)b * DIMD * NT + t0;
    float* qb = out_q + (size_t)b * DIMD * NT + t0;
    const int w = tid >> 6, lane = tid & 63;
    const int t = tid & 63, dg = tid >> 6;
    float lsum = 0.f;
    for (int dc = 0; dc < 8; ++dc) {
        for (int rr = 0; rr < 16; ++rr) {
            const int r = w * 16 + rr;
            q_lds[r][lane] = ncb[(size_t)codes[r] * DIMD + dc * 64 + lane];
        }
        __syncthreads();
        for (int m = 0; m < 16; ++m) {
            const int dl = dg * 16 + m;
            const int d = dc * 64 + dl;
            const float xv = xb[(size_t)d * NT + t];
            const float qv = q_lds[t][dl];
            qb[(size_t)d * NT + t] = qv;
            const float df = xv - qv;
            lsum += df * df;
        }
        __syncthreads();
    }
    for (int m = 32; m; m >>= 1) lsum += __shfl_xor(lsum, m);
    if (lane == 0) wred[w] = lsum;
    __syncthreads();
    if (tid == 0) atomicAdd(loss_sum, (wred[0] + wred[1]) + (wred[2] + wred[3]));
}

// ---------------- K6: finalize loss ----------------
__global__ void k_final(const float* __restrict__ scal, float* __restrict__ out) {
    out[O_LOSS] = scal[1] * (1.0f / 33554432.0f);
}

extern "C" void kernel_launch(void* const* d_in, const int* in_sizes, int n_in,
                              void* d_out, int out_size, void* d_ws, size_t ws_size,
                              hipStream_t stream) {
    const float* x        = (const float*)d_in[0];
    const float* cbw      = (const float*)d_in[1];
    const float* ema_size = (const float*)d_in[2];
    const float* ema_sum  = (const float*)d_in[3];
    float* out = (float*)d_out;
    float* wsf = (float*)d_ws;
    int*   widx = (int*)d_ws;
    float* csize = wsf + W_CSIZE;
    float* csum  = wsf + W_CSUM;
    float* norms = wsf + W_NORM;
    float* scal  = wsf + W_SCAL;
    int* flag_cnt = (int*)(wsf + W_FLAGCNT);
    int* flags    = (int*)(wsf + W_FLAGS);
    ushort* Bph   = (ushort*)(wsf + W_BPH);
    ushort* Bpl   = Bph + 524288;

    // zero csize/csum/norms/scal/flag_cnt in one shot
    hipMemsetAsync(csize, 0, (size_t)(W_FLAGCNT + 1 - W_CSIZE) * sizeof(float), stream);

    k_pack   <<<1024, 64, 0, stream>>>(cbw, Bph, Bpl);
    k_norms  <<<KCODES, 64, 0, stream>>>(cbw, norms);
    k_gemm_argmin<<<NROWS / 64, 512, 0, stream>>>(x, Bph, Bpl, norms, widx,
                                                  out + O_IDX, csize, csum,
                                                  flag_cnt, flags);
    k_refine <<<128, 256, 0, stream>>>(x, cbw, norms, flag_cnt, flags,
                                       widx, out + O_IDX, csize, csum);
    k_ema_size<<<1, 1024, 0, stream>>>(csize, ema_size, out, scal);
    k_codebook<<<(KCODES * DIMD) / 256, 256, 0, stream>>>(csum, ema_sum, scal, out);
    k_quant  <<<NROWS / 64, 256, 0, stream>>>(x, widx, out + O_NCB, out, scal + 1);
    k_final  <<<1, 1, 0, stream>>>(scal, out);
}